// Round 11
// baseline (131.696 us; speedup 1.0000x reference)
//
#include <hip/hip_runtime.h>
#include <hip/hip_bf16.h>
#include <cstdint>

typedef _Float16 f16;
typedef _Float16 f16x4 __attribute__((ext_vector_type(4)));
typedef _Float16 f16x8 __attribute__((ext_vector_type(8)));
typedef float f32x4 __attribute__((ext_vector_type(4)));

#define LNEG (-1e30f)
#define EXP2(x) __builtin_amdgcn_exp2f(x)   // bare v_exp_f32

__device__ __forceinline__ f32x4 mfma16(f16x8 a, f16x8 b, f32x4 c){
    return __builtin_amdgcn_mfma_f32_16x16x32_f16(a, b, c, 0, 0, 0);
}

// ---------- fused f32 -> f16 convert, 8 elems/thread ----------
__global__ __launch_bounds__(256) void cvt5(
    const float* __restrict__ x,  const float* __restrict__ wq,
    const float* __restrict__ wk, const float* __restrict__ wv,
    const float* __restrict__ wp, f16* __restrict__ dst, int nx8)
{
    int i = blockIdx.x * blockDim.x + threadIdx.x;
    const float* src; int off;
    if (i < nx8){ src = x; off = i; }
    else {
        int j = i - nx8;
        int s = j >> 17;              // WE/8 == 2^17
        off = j & 131071;
        src = (s == 0) ? wq : (s == 1) ? wk : (s == 2) ? wv : wp;
    }
    const float4* p = (const float4*)src + (size_t)off * 2;
    float4 v0 = p[0], v1 = p[1];
    f16x8 o = { (f16)v0.x, (f16)v0.y, (f16)v0.z, (f16)v0.w,
                (f16)v1.x, (f16)v1.y, (f16)v1.z, (f16)v1.w };
    *(f16x8*)&dst[(size_t)i * 8] = o;
}

// ---------- GEMM: reg-staged, XOR-swizzled LDS, double-buffered, 1 barrier/K-step ----
template<typename OutT>
__global__ __launch_bounds__(256) void gemm_xwt(
    const f16* __restrict__ A, const f16* __restrict__ W0, size_t wstride,
    OutT* __restrict__ out0, size_t ostride, f16* __restrict__ vtout,
    int M, int N, int K)
{
    const int tid  = threadIdx.x;
    const int lane = tid & 63;
    const int w    = tid >> 6;
    const int wr   = w >> 1, wc = w & 1;
    const int m0   = blockIdx.y * 128;
    const int n0   = blockIdx.x * 128;
    const f16* Wz  = W0 + wstride * blockIdx.z;
    OutT* out      = out0 + ostride * blockIdx.z;

    __shared__ f16 At[2][128 * 64];
    __shared__ f16 Bt[2][128 * 64];

    f32x4 acc[4][4] = {};
    f16x8 avr[4], bvr[4];

    int srow[4], scolb[4], sswz[4];
    #pragma unroll
    for (int j = 0; j < 4; ++j){
        int off  = (j * 256 + tid) * 16;
        srow[j]  = off >> 7;
        scolb[j] = off & 127;
        sswz[j]  = srow[j] * 128 + (scolb[j] ^ ((srow[j] & 7) << 4));
    }

    #pragma unroll
    for (int j = 0; j < 4; ++j){
        avr[j] = *(const f16x8*)&A [(size_t)(m0 + srow[j]) * K + (scolb[j] >> 1)];
        bvr[j] = *(const f16x8*)&Wz[(size_t)(n0 + srow[j]) * K + (scolb[j] >> 1)];
    }
    #pragma unroll
    for (int j = 0; j < 4; ++j){
        *(f16x8*)((char*)At[0] + sswz[j]) = avr[j];
        *(f16x8*)((char*)Bt[0] + sswz[j]) = bvr[j];
    }
    __syncthreads();

    const int NT = K >> 6;
    for (int t = 0; t < NT; ++t){
        const int cur = t & 1;
        const bool pre = (t + 1 < NT);
        if (pre){
            const int k0 = (t + 1) << 6;
            #pragma unroll
            for (int j = 0; j < 4; ++j){
                avr[j] = *(const f16x8*)&A [(size_t)(m0 + srow[j]) * K + k0 + (scolb[j] >> 1)];
                bvr[j] = *(const f16x8*)&Wz[(size_t)(n0 + srow[j]) * K + k0 + (scolb[j] >> 1)];
            }
        }
        #pragma unroll
        for (int kk = 0; kk < 2; ++kk){
            f16x8 af[4], bf[4];
            #pragma unroll
            for (int mf = 0; mf < 4; ++mf){
                int row = wr * 64 + mf * 16 + (lane & 15);
                int cb  = (kk * 64 + 16 * (lane >> 4)) ^ ((row & 7) << 4);
                af[mf] = *(const f16x8*)((const char*)At[cur] + row * 128 + cb);
            }
            #pragma unroll
            for (int nf = 0; nf < 4; ++nf){
                int row = wc * 64 + nf * 16 + (lane & 15);
                int cb  = (kk * 64 + 16 * (lane >> 4)) ^ ((row & 7) << 4);
                bf[nf] = *(const f16x8*)((const char*)Bt[cur] + row * 128 + cb);
            }
            #pragma unroll
            for (int mf = 0; mf < 4; ++mf)
                #pragma unroll
                for (int nf = 0; nf < 4; ++nf)
                    acc[mf][nf] = mfma16(af[mf], bf[nf], acc[mf][nf]);
        }
        if (pre){
            const int nb = cur ^ 1;
            #pragma unroll
            for (int j = 0; j < 4; ++j){
                *(f16x8*)((char*)At[nb] + sswz[j]) = avr[j];
                *(f16x8*)((char*)Bt[nb] + sswz[j]) = bvr[j];
            }
        }
        __syncthreads();
    }

    if (vtout != nullptr && blockIdx.z == 2){
        #pragma unroll
        for (int mf = 0; mf < 4; ++mf)
            #pragma unroll
            for (int nf = 0; nf < 4; ++nf){
                int row = m0 + wr * 64 + mf * 16 + 4 * (lane >> 4);
                int col = n0 + wc * 64 + nf * 16 + (lane & 15);
                int bb = row >> 11, ll = row & 2047;
                int bh = bb * 16 + (col >> 6), dd = col & 63;
                f16x4 o = { (f16)acc[mf][nf][0], (f16)acc[mf][nf][1],
                            (f16)acc[mf][nf][2], (f16)acc[mf][nf][3] };
                *(f16x4*)&vtout[((size_t)(bh * 64 + dd)) * 2048 + ll] = o;
            }
    } else {
        #pragma unroll
        for (int mf = 0; mf < 4; ++mf)
            #pragma unroll
            for (int nf = 0; nf < 4; ++nf)
                #pragma unroll
                for (int r = 0; r < 4; ++r){
                    int row = m0 + wr * 64 + mf * 16 + 4 * (lane >> 4) + r;
                    int col = n0 + wc * 64 + nf * 16 + (lane & 15);
                    out[(size_t)row * N + col] = (OutT)acc[mf][nf][r];
                }
    }
}

// ---------- fused causal flash attention: 32 q-rows/wave, two 16-row fragments ----------
// 512 blocks x 4 waves; block = 128 q-rows (qt*128..+127), wave w owns rows
// q0w..q0w+31 as fragments p=0 (rows +qq) and p=1 (rows +16+qq). Each K/V LDS
// read feeds 2 MFMAs; two independent softmax chains (ILP). Per-fragment code
// is the r7 body verbatim, unrolled over p (compile-time indices only).
// Pairing remap: co-resident blocks (lin, lin+256) -> (qt, 15-qt), 34 tiles.
__global__ __launch_bounds__(256, 2) void attn_fused(
    const f16* __restrict__ q, const f16* __restrict__ k,
    const f16* __restrict__ vt, const int* __restrict__ amask,
    f16* __restrict__ y)
{
    const int tid  = threadIdx.x;
    const int lane = tid & 63;
    const int w    = tid >> 6;
    const int g    = lane >> 4;
    const int qq   = lane & 15;

    const int lin = blockIdx.x;
    const int bh  = ((lin & 7) << 2) | ((lin >> 3) & 3);   // same head -> same XCD
    const int qtI = (lin >> 5) & 15;
    const int qt  = (qtI < 8) ? qtI : 23 - qtI;            // pairs (t, 15-t)
    const int b = bh >> 4, h = bh & 15;
    const int q0w = qt * 128 + w * 32;
    const int nkt = 2 * qt + 2;

    __shared__ char sK[2][64 * 128];
    __shared__ char sV[2][64 * 128];
    __shared__ char sP[4][2][16 * 128];

    const int srow = (tid * 2) >> 3;
    const int sc8a = (tid * 2) & 7, sc8b = sc8a + 1;
    const int swka = (sc8a * 16) ^ ((srow & 7) << 4);
    const int swkb = (sc8b * 16) ^ ((srow & 7) << 4);
    const f16* kbase  = k  + ((size_t)b * 2048) * 1024 + h * 64;
    const f16* vtbase = vt + (size_t)bh * 64 * 2048;

    const f16 qscale = (f16)(0.125f * 1.44269504088896f);
    f16x8 aq[2][2];
    #pragma unroll
    for (int p = 0; p < 2; ++p)
        #pragma unroll
        for (int f = 0; f < 2; ++f){
            aq[p][f] = *(const f16x8*)&q[((size_t)(b * 2048 + q0w + 16 * p + qq)) * 1024 + h * 64 + f * 32 + 8 * g];
            #pragma unroll
            for (int j = 0; j < 8; ++j) aq[p][f][j] *= qscale;
        }

    f32x4 acc_o[2][4] = {};
    float m_st[2] = { LNEG, LNEG }, l_st[2] = { 0.f, 0.f };
    const int swp = (qq & 7) << 4;

    {   // prologue: tile 0 -> buf0
        f16x8 ka  = *(const f16x8*)(kbase  + (size_t)srow * 1024 + sc8a * 8);
        f16x8 kb2 = *(const f16x8*)(kbase  + (size_t)srow * 1024 + sc8b * 8);
        f16x8 va  = *(const f16x8*)(vtbase + (size_t)srow * 2048 + sc8a * 8);
        f16x8 vb  = *(const f16x8*)(vtbase + (size_t)srow * 2048 + sc8b * 8);
        *(f16x8*)(sK[0] + srow * 128 + swka) = ka;
        *(f16x8*)(sK[0] + srow * 128 + swkb) = kb2;
        *(f16x8*)(sV[0] + srow * 128 + swka) = va;
        *(f16x8*)(sV[0] + srow * 128 + swkb) = vb;
    }
    __syncthreads();

    for (int kt = 0; kt < nkt; ++kt){
        const int cur = kt & 1;
        const int k0 = kt * 64;
        const bool pre = (kt + 1 < nkt);

        f16x8 ka, kb2, va, vb;
        if (pre){
            const int nk0 = k0 + 64;
            ka  = *(const f16x8*)(kbase  + (size_t)(nk0 + srow) * 1024 + sc8a * 8);
            kb2 = *(const f16x8*)(kbase  + (size_t)(nk0 + srow) * 1024 + sc8b * 8);
            va  = *(const f16x8*)(vtbase + (size_t)srow * 2048 + nk0 + sc8a * 8);
            vb  = *(const f16x8*)(vtbase + (size_t)srow * 2048 + nk0 + sc8b * 8);
        }

        unsigned long long tokbits = __ballot(amask[b * 2048 + k0 + lane] != 0);
        const bool tokall = (tokbits == ~0ull);

        // QK^T: each K fragment feeds both q-fragments
        f32x4 accS[2][4] = {};
        #pragma unroll
        for (int kf = 0; kf < 4; ++kf){
            const int keyl = kf * 16 + qq;
            const char* kr = sK[cur] + keyl * 128;
            const int sw = (keyl & 7) << 4;
            #pragma unroll
            for (int f = 0; f < 2; ++f){
                f16x8 ak = *(const f16x8*)(kr + ((f * 64 + 16 * g) ^ sw));
                accS[0][kf] = mfma16(ak, aq[0][f], accS[0][kf]);
                accS[1][kf] = mfma16(ak, aq[1][f], accS[1][kf]);
            }
        }

        // two independent softmax chains (r7 body per fragment)
        #pragma unroll
        for (int p = 0; p < 2; ++p){
            const int q0p = q0w + 16 * p;
            const bool fullt = (k0 + 63 <= q0p) && tokall;
            float sv[16];
            #pragma unroll
            for (int kf = 0; kf < 4; ++kf)
                #pragma unroll
                for (int r = 0; r < 4; ++r){
                    float s = accS[p][kf][r];
                    if (!fullt){
                        const int keyl = kf * 16 + 4 * g + r;
                        const bool ok = (k0 + keyl <= q0p + qq) && ((tokbits >> keyl) & 1);
                        s = ok ? s : LNEG;
                    }
                    sv[kf * 4 + r] = s;
                }

            float tmax = sv[0];
            #pragma unroll
            for (int i = 1; i < 16; ++i) tmax = fmaxf(tmax, sv[i]);
            tmax = fmaxf(tmax, __shfl_xor(tmax, 16));
            tmax = fmaxf(tmax, __shfl_xor(tmax, 32));
            const bool skip = __all(tmax <= m_st[p] + 8.f);   // defer-max (log2)
            float alpha = 1.f;
            if (!skip){
                const float newm = fmaxf(m_st[p], tmax);
                alpha = EXP2(m_st[p] - newm);
                m_st[p] = newm;
            }
            float rs = 0.f;
            #pragma unroll
            for (int i = 0; i < 16; ++i){ sv[i] = EXP2(sv[i] - m_st[p]); rs += sv[i]; }
            rs += __shfl_xor(rs, 16);
            rs += __shfl_xor(rs, 32);
            l_st[p] = l_st[p] * alpha + rs;
            if (!skip){
                #pragma unroll
                for (int r = 0; r < 4; ++r){
                    const float ar = __shfl(alpha, 4 * g + r);
                    #pragma unroll
                    for (int nf = 0; nf < 4; ++nf) acc_o[p][nf][r] *= ar;
                }
            }

            char* pbase = sP[w][p] + qq * 128;
            #pragma unroll
            for (int kf = 0; kf < 4; ++kf){
                f16x4 pk = { (f16)sv[kf*4+0], (f16)sv[kf*4+1], (f16)sv[kf*4+2], (f16)sv[kf*4+3] };
                *(f16x4*)(pbase + ((kf * 32 + 8 * g) ^ swp)) = pk;
            }
        }
        __builtin_amdgcn_wave_barrier();

        // PV: each V fragment feeds both q-fragments
        #pragma unroll
        for (int f = 0; f < 2; ++f){
            f16x8 apA = *(const f16x8*)(sP[w][0] + qq * 128 + ((f * 64 + 16 * g) ^ swp));
            f16x8 apB = *(const f16x8*)(sP[w][1] + qq * 128 + ((f * 64 + 16 * g) ^ swp));
            #pragma unroll
            for (int nf = 0; nf < 4; ++nf){
                const int d = nf * 16 + qq;
                f16x8 bv = *(const f16x8*)(sV[cur] + d * 128 + ((f * 64 + 16 * g) ^ ((d & 7) << 4)));
                acc_o[0][nf] = mfma16(apA, bv, acc_o[0][nf]);
                acc_o[1][nf] = mfma16(apB, bv, acc_o[1][nf]);
            }
        }
        __builtin_amdgcn_wave_barrier();

        if (pre){
            const int nb = cur ^ 1;
            *(f16x8*)(sK[nb] + srow * 128 + swka) = ka;
            *(f16x8*)(sK[nb] + srow * 128 + swkb) = kb2;
            *(f16x8*)(sV[nb] + srow * 128 + swka) = va;
            *(f16x8*)(sV[nb] + srow * 128 + swkb) = vb;
        }
        __syncthreads();
    }

    #pragma unroll
    for (int p = 0; p < 2; ++p){
        const float invl = 1.f / l_st[p];
        #pragma unroll
        for (int r = 0; r < 4; ++r){
            const float ir = __shfl(invl, 4 * g + r);
            const int row = q0w + 16 * p + 4 * g + r;
            #pragma unroll
            for (int nf = 0; nf < 4; ++nf)
                y[((size_t)(b * 2048 + row)) * 1024 + h * 64 + nf * 16 + qq] = (f16)(acc_o[p][nf][r] * ir);
        }
    }
}

extern "C" void kernel_launch(void* const* d_in, const int* in_sizes, int n_in,
                              void* d_out, int out_size, void* d_ws, size_t ws_size,
                              hipStream_t stream){
    const float* x  = (const float*)d_in[0];
    const int*   am = (const int*)d_in[1];
    const float* Wq = (const float*)d_in[2];
    const float* Wk = (const float*)d_in[3];
    const float* Wv = (const float*)d_in[4];
    const float* Wp = (const float*)d_in[5];
    float* out = (float*)d_out;

    char* ws = (char*)d_ws;
    const size_t XE = (size_t)4096 * 1024;
    const size_t WE = (size_t)1024 * 1024;

    f16* x16 = (f16*)(ws);
    f16* w16 = (f16*)(ws + XE * 2);
    f16* qkv = (f16*)(ws + XE * 2 + WE * 8);
    f16* vt  = (f16*)(ws + XE * 2 + WE * 8 + XE * 6);
    f16* y16 = (f16*)(ws + XE * 2 + WE * 8 + XE * 8);

    cvt5<<<4096, 256, 0, stream>>>(x, Wq, Wk, Wv, Wp, x16, (int)(XE / 8));

    gemm_xwt<f16><<<dim3(8, 32, 3), 256, 0, stream>>>(x16, w16, WE, qkv, XE, vt, 4096, 1024, 1024);

    attn_fused<<<dim3(512), 256, 0, stream>>>(qkv, qkv + XE, vt, am, y16);

    gemm_xwt<float><<<dim3(8, 32, 1), 256, 0, stream>>>(y16, w16 + 3 * WE, 0, out, 0, nullptr, 4096, 1024, 1024);
}

// Round 13
// 110.667 us; speedup vs baseline: 1.1900x; 1.1900x over previous
//
#include <hip/hip_runtime.h>
#include <hip/hip_bf16.h>
#include <cstdint>

typedef _Float16 f16;
typedef _Float16 f16x4 __attribute__((ext_vector_type(4)));
typedef _Float16 f16x8 __attribute__((ext_vector_type(8)));
typedef float f32x4 __attribute__((ext_vector_type(4)));

#define LNEG (-1e30f)
#define EXP2(x) __builtin_amdgcn_exp2f(x)   // bare v_exp_f32

__device__ __forceinline__ f32x4 mfma16(f16x8 a, f16x8 b, f32x4 c){
    return __builtin_amdgcn_mfma_f32_16x16x32_f16(a, b, c, 0, 0, 0);
}

// ---------- fused f32 -> f16 convert, 8 elems/thread ----------
__global__ __launch_bounds__(256) void cvt5(
    const float* __restrict__ x,  const float* __restrict__ wq,
    const float* __restrict__ wk, const float* __restrict__ wv,
    const float* __restrict__ wp, f16* __restrict__ dst, int nx8)
{
    int i = blockIdx.x * blockDim.x + threadIdx.x;
    const float* src; int off;
    if (i < nx8){ src = x; off = i; }
    else {
        int j = i - nx8;
        int s = j >> 17;              // WE/8 == 2^17
        off = j & 131071;
        src = (s == 0) ? wq : (s == 1) ? wk : (s == 2) ? wv : wp;
    }
    const float4* p = (const float4*)src + (size_t)off * 2;
    float4 v0 = p[0], v1 = p[1];
    f16x8 o = { (f16)v0.x, (f16)v0.y, (f16)v0.z, (f16)v0.w,
                (f16)v1.x, (f16)v1.y, (f16)v1.z, (f16)v1.w };
    *(f16x8*)&dst[(size_t)i * 8] = o;
}

// ---------- GEMM: reg-staged, XOR-swizzled LDS, double-buffered, 1 barrier/K-step ----
template<typename OutT>
__global__ __launch_bounds__(256) void gemm_xwt(
    const f16* __restrict__ A, const f16* __restrict__ W0, size_t wstride,
    OutT* __restrict__ out0, size_t ostride, f16* __restrict__ vtout,
    int M, int N, int K)
{
    const int tid  = threadIdx.x;
    const int lane = tid & 63;
    const int w    = tid >> 6;
    const int wr   = w >> 1, wc = w & 1;
    const int m0   = blockIdx.y * 128;
    const int n0   = blockIdx.x * 128;
    const f16* Wz  = W0 + wstride * blockIdx.z;
    OutT* out      = out0 + ostride * blockIdx.z;

    __shared__ f16 At[2][128 * 64];
    __shared__ f16 Bt[2][128 * 64];

    f32x4 acc[4][4] = {};
    f16x8 avr[4], bvr[4];

    int srow[4], scolb[4], sswz[4];
    #pragma unroll
    for (int j = 0; j < 4; ++j){
        int off  = (j * 256 + tid) * 16;
        srow[j]  = off >> 7;
        scolb[j] = off & 127;
        sswz[j]  = srow[j] * 128 + (scolb[j] ^ ((srow[j] & 7) << 4));
    }

    #pragma unroll
    for (int j = 0; j < 4; ++j){
        avr[j] = *(const f16x8*)&A [(size_t)(m0 + srow[j]) * K + (scolb[j] >> 1)];
        bvr[j] = *(const f16x8*)&Wz[(size_t)(n0 + srow[j]) * K + (scolb[j] >> 1)];
    }
    #pragma unroll
    for (int j = 0; j < 4; ++j){
        *(f16x8*)((char*)At[0] + sswz[j]) = avr[j];
        *(f16x8*)((char*)Bt[0] + sswz[j]) = bvr[j];
    }
    __syncthreads();

    const int NT = K >> 6;
    for (int t = 0; t < NT; ++t){
        const int cur = t & 1;
        const bool pre = (t + 1 < NT);
        if (pre){
            const int k0 = (t + 1) << 6;
            #pragma unroll
            for (int j = 0; j < 4; ++j){
                avr[j] = *(const f16x8*)&A [(size_t)(m0 + srow[j]) * K + k0 + (scolb[j] >> 1)];
                bvr[j] = *(const f16x8*)&Wz[(size_t)(n0 + srow[j]) * K + k0 + (scolb[j] >> 1)];
            }
        }
        #pragma unroll
        for (int kk = 0; kk < 2; ++kk){
            f16x8 af[4], bf[4];
            #pragma unroll
            for (int mf = 0; mf < 4; ++mf){
                int row = wr * 64 + mf * 16 + (lane & 15);
                int cb  = (kk * 64 + 16 * (lane >> 4)) ^ ((row & 7) << 4);
                af[mf] = *(const f16x8*)((const char*)At[cur] + row * 128 + cb);
            }
            #pragma unroll
            for (int nf = 0; nf < 4; ++nf){
                int row = wc * 64 + nf * 16 + (lane & 15);
                int cb  = (kk * 64 + 16 * (lane >> 4)) ^ ((row & 7) << 4);
                bf[nf] = *(const f16x8*)((const char*)Bt[cur] + row * 128 + cb);
            }
            #pragma unroll
            for (int mf = 0; mf < 4; ++mf)
                #pragma unroll
                for (int nf = 0; nf < 4; ++nf)
                    acc[mf][nf] = mfma16(af[mf], bf[nf], acc[mf][nf]);
        }
        if (pre){
            const int nb = cur ^ 1;
            #pragma unroll
            for (int j = 0; j < 4; ++j){
                *(f16x8*)((char*)At[nb] + sswz[j]) = avr[j];
                *(f16x8*)((char*)Bt[nb] + sswz[j]) = bvr[j];
            }
        }
        __syncthreads();
    }

    if (vtout != nullptr && blockIdx.z == 2){
        #pragma unroll
        for (int mf = 0; mf < 4; ++mf)
            #pragma unroll
            for (int nf = 0; nf < 4; ++nf){
                int row = m0 + wr * 64 + mf * 16 + 4 * (lane >> 4);
                int col = n0 + wc * 64 + nf * 16 + (lane & 15);
                int bb = row >> 11, ll = row & 2047;
                int bh = bb * 16 + (col >> 6), dd = col & 63;
                f16x4 o = { (f16)acc[mf][nf][0], (f16)acc[mf][nf][1],
                            (f16)acc[mf][nf][2], (f16)acc[mf][nf][3] };
                *(f16x4*)&vtout[((size_t)(bh * 64 + dd)) * 2048 + ll] = o;
            }
    } else {
        #pragma unroll
        for (int mf = 0; mf < 4; ++mf)
            #pragma unroll
            for (int nf = 0; nf < 4; ++nf)
                #pragma unroll
                for (int r = 0; r < 4; ++r){
                    int row = m0 + wr * 64 + mf * 16 + 4 * (lane >> 4) + r;
                    int col = n0 + wc * 64 + nf * 16 + (lane & 15);
                    out[(size_t)row * N + col] = (OutT)acc[mf][nf][r];
                }
    }
}

// ---------- fused causal flash attention (split-k, hardened P barrier) ----------
// 1408 blocks, LPT order. qt<20: full range, final y. qt>=20: partA kt[0,16)
// + partB kt[16,qt+1); partials = unnormalized f32 O + (m,l), merged after.
// P write->read ordered by a REAL __syncthreads (wave_barrier has no HW wait).
__global__ __launch_bounds__(256, 4) void attn_fused(
    const f16* __restrict__ q, const f16* __restrict__ k,
    const f16* __restrict__ vt, const int* __restrict__ amask,
    f16* __restrict__ y, float* __restrict__ pO, float* __restrict__ pML)
{
    const int tid  = threadIdx.x;
    const int lane = tid & 63;
    const int w    = tid >> 6;
    const int g    = lane >> 4;
    const int qq   = lane & 15;

    const int lin = blockIdx.x;
    const int bh  = lin & 31;
    const int grp = lin >> 5;
    int qt, ktLo, ktHi, part; bool fin;
    if (grp < 4)      { qt = 19 - grp;  ktLo = 0;  ktHi = qt + 1; fin = true;  part = 0; }
    else if (grp < 16){ qt = 16 + grp;  ktLo = 0;  ktHi = 16;     fin = false; part = 0; }
    else if (grp < 28){ qt = 47 - grp;  ktLo = 16; ktHi = qt + 1; fin = false; part = 1; }
    else              { qt = 43 - grp;  ktLo = 0;  ktHi = qt + 1; fin = true;  part = 0; }

    const int b = bh >> 4, h = bh & 15;
    const int q0w = qt * 64 + w * 16;

    __shared__ char sK[2][64 * 128];
    __shared__ char sV[2][64 * 128];
    __shared__ char sP[4][16 * 128];

    const int srow = (tid * 2) >> 3;
    const int sc8a = (tid * 2) & 7, sc8b = sc8a + 1;
    const int swka = (sc8a * 16) ^ ((srow & 7) << 4);
    const int swkb = (sc8b * 16) ^ ((srow & 7) << 4);
    const f16* kbase  = k  + ((size_t)b * 2048) * 1024 + h * 64;
    const f16* vtbase = vt + (size_t)bh * 64 * 2048;

    const f16 qscale = (f16)(0.125f * 1.44269504088896f);
    f16x8 aq[2];
    #pragma unroll
    for (int f = 0; f < 2; ++f){
        aq[f] = *(const f16x8*)&q[((size_t)(b * 2048 + q0w + qq)) * 1024 + h * 64 + f * 32 + 8 * g];
        #pragma unroll
        for (int j = 0; j < 8; ++j) aq[f][j] *= qscale;
    }

    f32x4 acc_o[4] = {};
    float m_ln = LNEG, l_ln = 0.f;

    char* pbase = sP[w] + qq * 128;
    const int swp = (qq & 7) << 4;

    {   // prologue: stage tile ktLo into buf0
        const int k0p = ktLo * 64;
        f16x8 ka  = *(const f16x8*)(kbase  + (size_t)(k0p + srow) * 1024 + sc8a * 8);
        f16x8 kb2 = *(const f16x8*)(kbase  + (size_t)(k0p + srow) * 1024 + sc8b * 8);
        f16x8 va  = *(const f16x8*)(vtbase + (size_t)srow * 2048 + k0p + sc8a * 8);
        f16x8 vb  = *(const f16x8*)(vtbase + (size_t)srow * 2048 + k0p + sc8b * 8);
        *(f16x8*)(sK[0] + srow * 128 + swka) = ka;
        *(f16x8*)(sK[0] + srow * 128 + swkb) = kb2;
        *(f16x8*)(sV[0] + srow * 128 + swka) = va;
        *(f16x8*)(sV[0] + srow * 128 + swkb) = vb;
    }
    __syncthreads();

    for (int kt = ktLo; kt < ktHi; ++kt){
        const int cur = (kt - ktLo) & 1;
        const int k0 = kt * 64;
        const bool pre = (kt + 1 < ktHi);

        f16x8 ka, kb2, va, vb;
        if (pre){
            const int nk0 = k0 + 64;
            ka  = *(const f16x8*)(kbase  + (size_t)(nk0 + srow) * 1024 + sc8a * 8);
            kb2 = *(const f16x8*)(kbase  + (size_t)(nk0 + srow) * 1024 + sc8b * 8);
            va  = *(const f16x8*)(vtbase + (size_t)srow * 2048 + nk0 + sc8a * 8);
            vb  = *(const f16x8*)(vtbase + (size_t)srow * 2048 + nk0 + sc8b * 8);
        }

        unsigned long long tokbits = __ballot(amask[b * 2048 + k0 + lane] != 0);
        const bool tokall = (tokbits == ~0ull);

        f32x4 acc_s[4] = {};
        #pragma unroll
        for (int kf = 0; kf < 4; ++kf){
            const int keyl = kf * 16 + qq;
            const char* kr = sK[cur] + keyl * 128;
            const int sw = (keyl & 7) << 4;
            #pragma unroll
            for (int f = 0; f < 2; ++f){
                f16x8 ak = *(const f16x8*)(kr + ((f * 64 + 16 * g) ^ sw));
                acc_s[kf] = mfma16(ak, aq[f], acc_s[kf]);
            }
        }

        const bool fullt = (k0 + 63 <= q0w) && tokall;
        float sv[16];
        #pragma unroll
        for (int kf = 0; kf < 4; ++kf)
            #pragma unroll
            for (int r = 0; r < 4; ++r){
                float s = acc_s[kf][r];
                if (!fullt){
                    const int keyl = kf * 16 + 4 * g + r;
                    const bool ok = (k0 + keyl <= q0w + qq) && ((tokbits >> keyl) & 1);
                    s = ok ? s : LNEG;
                }
                sv[kf * 4 + r] = s;
            }

        float tmax = sv[0];
        #pragma unroll
        for (int i = 1; i < 16; ++i) tmax = fmaxf(tmax, sv[i]);
        tmax = fmaxf(tmax, __shfl_xor(tmax, 16));
        tmax = fmaxf(tmax, __shfl_xor(tmax, 32));
        const bool skip = __all(tmax <= m_ln + 8.f);   // defer-max (log2 units)
        float alpha = 1.f;
        if (!skip){
            const float newm = fmaxf(m_ln, tmax);
            alpha = EXP2(m_ln - newm);
            m_ln = newm;
        }
        float rs = 0.f;
        #pragma unroll
        for (int i = 0; i < 16; ++i){ sv[i] = EXP2(sv[i] - m_ln); rs += sv[i]; }
        rs += __shfl_xor(rs, 16);
        rs += __shfl_xor(rs, 32);
        l_ln = l_ln * alpha + rs;
        if (!skip){
            #pragma unroll
            for (int r = 0; r < 4; ++r){
                const float ar = __shfl(alpha, 4 * g + r);
                #pragma unroll
                for (int nf = 0; nf < 4; ++nf) acc_o[nf][r] *= ar;
            }
        }

        #pragma unroll
        for (int kf = 0; kf < 4; ++kf){
            f16x4 pk = { (f16)sv[kf*4+0], (f16)sv[kf*4+1], (f16)sv[kf*4+2], (f16)sv[kf*4+3] };
            *(f16x4*)(pbase + ((kf * 32 + 8 * g) ^ swp)) = pk;
        }
        __syncthreads();   // REAL fence: P stores drained before P reads

        #pragma unroll
        for (int f = 0; f < 2; ++f){
            f16x8 ap = *(const f16x8*)(pbase + ((f * 64 + 16 * g) ^ swp));
            #pragma unroll
            for (int nf = 0; nf < 4; ++nf){
                const int d = nf * 16 + qq;
                f16x8 bv = *(const f16x8*)(sV[cur] + d * 128 + ((f * 64 + 16 * g) ^ ((d & 7) << 4)));
                acc_o[nf] = mfma16(ap, bv, acc_o[nf]);
            }
        }

        if (pre){
            const int nb = cur ^ 1;
            *(f16x8*)(sK[nb] + srow * 128 + swka) = ka;
            *(f16x8*)(sK[nb] + srow * 128 + swkb) = kb2;
            *(f16x8*)(sV[nb] + srow * 128 + swka) = va;
            *(f16x8*)(sV[nb] + srow * 128 + swkb) = vb;
        }
        __syncthreads();   // P consumed + next buffers staged
    }

    if (fin){
        const float invl = 1.f / l_ln;
        #pragma unroll
        for (int r = 0; r < 4; ++r){
            const float ir = __shfl(invl, 4 * g + r);
            const int row = q0w + 4 * g + r;
            #pragma unroll
            for (int nf = 0; nf < 4; ++nf)
                y[((size_t)(b * 2048 + row)) * 1024 + h * 64 + nf * 16 + qq] = (f16)(acc_o[nf][r] * ir);
        }
    } else {
        const int qi = qt - 20;
        const size_t base = (((size_t)part * 12 + qi) * 32 + bh) * 64;
        #pragma unroll
        for (int r = 0; r < 4; ++r){
            const int row_local = w * 16 + 4 * g + r;
            float* po = pO + (base + row_local) * 64;
            #pragma unroll
            for (int nf = 0; nf < 4; ++nf)
                po[nf * 16 + qq] = acc_o[nf][r];
        }
        if (lane < 16){
            const size_t mlb = (base + w * 16 + lane) * 2;
            pML[mlb]     = m_ln;
            pML[mlb + 1] = l_ln;
        }
    }
}

// ---------- merge partials for qt 20..31 (rows 1280..2047) ----------
__global__ __launch_bounds__(256) void attn_merge(
    const float* __restrict__ pO, const float* __restrict__ pML, f16* __restrict__ y)
{
    const int t = blockIdx.x * 256 + threadIdx.x;   // 98304 threads
    const int dc = (t & 3) * 16;
    const int rowg = t >> 2;                         // 24576
    const int row = rowg & 63;
    const int bh  = (rowg >> 6) & 31;
    const int qi  = rowg >> 11;                      // 0..11
    const size_t rbase = ((size_t)qi * 32 + bh) * 64 + row;
    const size_t PST = (size_t)12 * 32 * 64;         // rows per part

    const float mA = pML[rbase * 2],         lA = pML[rbase * 2 + 1];
    const float mB = pML[(PST + rbase) * 2], lB = pML[(PST + rbase) * 2 + 1];
    const float m  = fmaxf(mA, mB);
    const float wA = EXP2(mA - m), wB = EXP2(mB - m);
    const float inv = 1.f / (wA * lA + wB * lB);

    const float4* oA = (const float4*)(pO + rbase * 64 + dc);
    const float4* oB = (const float4*)(pO + (PST * 64) + rbase * 64 + dc);
    float ov[16];
    #pragma unroll
    for (int j = 0; j < 4; ++j){
        float4 a = oA[j], bb4 = oB[j];
        ov[j*4+0] = (wA * a.x + wB * bb4.x) * inv;
        ov[j*4+1] = (wA * a.y + wB * bb4.y) * inv;
        ov[j*4+2] = (wA * a.z + wB * bb4.z) * inv;
        ov[j*4+3] = (wA * a.w + wB * bb4.w) * inv;
    }
    const int b = bh >> 4, h = bh & 15;
    const int grow = (20 + qi) * 64 + row;           // 1280..2047
    f16* yp = &y[((size_t)(b * 2048 + grow)) * 1024 + h * 64 + dc];
    f16x8 o0 = { (f16)ov[0],(f16)ov[1],(f16)ov[2],(f16)ov[3],(f16)ov[4],(f16)ov[5],(f16)ov[6],(f16)ov[7] };
    f16x8 o1 = { (f16)ov[8],(f16)ov[9],(f16)ov[10],(f16)ov[11],(f16)ov[12],(f16)ov[13],(f16)ov[14],(f16)ov[15] };
    *(f16x8*)yp = o0;
    *(f16x8*)(yp + 8) = o1;
}

extern "C" void kernel_launch(void* const* d_in, const int* in_sizes, int n_in,
                              void* d_out, int out_size, void* d_ws, size_t ws_size,
                              hipStream_t stream){
    const float* x  = (const float*)d_in[0];
    const int*   am = (const int*)d_in[1];
    const float* Wq = (const float*)d_in[2];
    const float* Wk = (const float*)d_in[3];
    const float* Wv = (const float*)d_in[4];
    const float* Wp = (const float*)d_in[5];
    float* out = (float*)d_out;

    char* ws = (char*)d_ws;
    const size_t XE = (size_t)4096 * 1024;
    const size_t WE = (size_t)1024 * 1024;

    f16* x16 = (f16*)(ws);
    f16* w16 = (f16*)(ws + XE * 2);
    f16* qkv = (f16*)(ws + XE * 2 + WE * 8);
    f16* vt  = (f16*)(ws + XE * 2 + WE * 8 + XE * 6);
    f16* y16 = (f16*)(ws + XE * 2 + WE * 8 + XE * 8);
    // partial buffers overlay x16 + Wq/Wk/part-of-Wv (dead after QKV GEMM; Wp @ +14MB safe)
    float* pO  = (float*)ws;
    float* pML = (float*)(ws + (size_t)2*12*32*64*64*4);

    cvt5<<<4096, 256, 0, stream>>>(x, Wq, Wk, Wv, Wp, x16, (int)(XE / 8));

    gemm_xwt<f16><<<dim3(8, 32, 3), 256, 0, stream>>>(x16, w16, WE, qkv, XE, vt, 4096, 1024, 1024);

    attn_fused<<<dim3(1408), 256, 0, stream>>>(qkv, qkv + XE, vt, am, y16, pO, pML);

    attn_merge<<<384, 256, 0, stream>>>(pO, pML, y16);

    gemm_xwt<float><<<dim3(8, 32, 1), 256, 0, stream>>>(y16, w16 + 3 * WE, 0, out, 0, nullptr, 4096, 1024, 1024);
}

// Round 14
// 108.576 us; speedup vs baseline: 1.2129x; 1.0193x over previous
//
#include <hip/hip_runtime.h>
#include <hip/hip_bf16.h>
#include <cstdint>

typedef _Float16 f16;
typedef _Float16 f16x4 __attribute__((ext_vector_type(4)));
typedef _Float16 f16x8 __attribute__((ext_vector_type(8)));
typedef float f32x4 __attribute__((ext_vector_type(4)));

#define LNEG (-1e30f)
#define EXP2(x) __builtin_amdgcn_exp2f(x)   // bare v_exp_f32

__device__ __forceinline__ f32x4 mfma16(f16x8 a, f16x8 b, f32x4 c){
    return __builtin_amdgcn_mfma_f32_16x16x32_f16(a, b, c, 0, 0, 0);
}

// ---------- fused f32 -> f16 convert, 8 elems/thread ----------
__global__ __launch_bounds__(256) void cvt5(
    const float* __restrict__ x,  const float* __restrict__ wq,
    const float* __restrict__ wk, const float* __restrict__ wv,
    const float* __restrict__ wp, f16* __restrict__ dst, int nx8)
{
    int i = blockIdx.x * blockDim.x + threadIdx.x;
    const float* src; int off;
    if (i < nx8){ src = x; off = i; }
    else {
        int j = i - nx8;
        int s = j >> 17;              // WE/8 == 2^17
        off = j & 131071;
        src = (s == 0) ? wq : (s == 1) ? wk : (s == 2) ? wv : wp;
    }
    const float4* p = (const float4*)src + (size_t)off * 2;
    float4 v0 = p[0], v1 = p[1];
    f16x8 o = { (f16)v0.x, (f16)v0.y, (f16)v0.z, (f16)v0.w,
                (f16)v1.x, (f16)v1.y, (f16)v1.z, (f16)v1.w };
    *(f16x8*)&dst[(size_t)i * 8] = o;
}

// ---------- GEMM 128x128 (QKV): reg-staged, swizzled LDS, dbuf, 1 barrier/K-step ----
template<typename OutT>
__global__ __launch_bounds__(256) void gemm_xwt(
    const f16* __restrict__ A, const f16* __restrict__ W0, size_t wstride,
    OutT* __restrict__ out0, size_t ostride, f16* __restrict__ vtout,
    int M, int N, int K)
{
    const int tid  = threadIdx.x;
    const int lane = tid & 63;
    const int w    = tid >> 6;
    const int wr   = w >> 1, wc = w & 1;
    const int m0   = blockIdx.y * 128;
    const int n0   = blockIdx.x * 128;
    const f16* Wz  = W0 + wstride * blockIdx.z;
    OutT* out      = out0 + ostride * blockIdx.z;

    __shared__ f16 At[2][128 * 64];
    __shared__ f16 Bt[2][128 * 64];

    f32x4 acc[4][4] = {};
    f16x8 avr[4], bvr[4];

    int srow[4], scolb[4], sswz[4];
    #pragma unroll
    for (int j = 0; j < 4; ++j){
        int off  = (j * 256 + tid) * 16;
        srow[j]  = off >> 7;
        scolb[j] = off & 127;
        sswz[j]  = srow[j] * 128 + (scolb[j] ^ ((srow[j] & 7) << 4));
    }

    #pragma unroll
    for (int j = 0; j < 4; ++j){
        avr[j] = *(const f16x8*)&A [(size_t)(m0 + srow[j]) * K + (scolb[j] >> 1)];
        bvr[j] = *(const f16x8*)&Wz[(size_t)(n0 + srow[j]) * K + (scolb[j] >> 1)];
    }
    #pragma unroll
    for (int j = 0; j < 4; ++j){
        *(f16x8*)((char*)At[0] + sswz[j]) = avr[j];
        *(f16x8*)((char*)Bt[0] + sswz[j]) = bvr[j];
    }
    __syncthreads();

    const int NT = K >> 6;
    for (int t = 0; t < NT; ++t){
        const int cur = t & 1;
        const bool pre = (t + 1 < NT);
        if (pre){
            const int k0 = (t + 1) << 6;
            #pragma unroll
            for (int j = 0; j < 4; ++j){
                avr[j] = *(const f16x8*)&A [(size_t)(m0 + srow[j]) * K + k0 + (scolb[j] >> 1)];
                bvr[j] = *(const f16x8*)&Wz[(size_t)(n0 + srow[j]) * K + k0 + (scolb[j] >> 1)];
            }
        }
        #pragma unroll
        for (int kk = 0; kk < 2; ++kk){
            f16x8 af[4], bf[4];
            #pragma unroll
            for (int mf = 0; mf < 4; ++mf){
                int row = wr * 64 + mf * 16 + (lane & 15);
                int cb  = (kk * 64 + 16 * (lane >> 4)) ^ ((row & 7) << 4);
                af[mf] = *(const f16x8*)((const char*)At[cur] + row * 128 + cb);
            }
            #pragma unroll
            for (int nf = 0; nf < 4; ++nf){
                int row = wc * 64 + nf * 16 + (lane & 15);
                int cb  = (kk * 64 + 16 * (lane >> 4)) ^ ((row & 7) << 4);
                bf[nf] = *(const f16x8*)((const char*)Bt[cur] + row * 128 + cb);
            }
            #pragma unroll
            for (int mf = 0; mf < 4; ++mf)
                #pragma unroll
                for (int nf = 0; nf < 4; ++nf)
                    acc[mf][nf] = mfma16(af[mf], bf[nf], acc[mf][nf]);
        }
        if (pre){
            const int nb = cur ^ 1;
            #pragma unroll
            for (int j = 0; j < 4; ++j){
                *(f16x8*)((char*)At[nb] + sswz[j]) = avr[j];
                *(f16x8*)((char*)Bt[nb] + sswz[j]) = bvr[j];
            }
        }
        __syncthreads();
    }

    if (vtout != nullptr && blockIdx.z == 2){
        #pragma unroll
        for (int mf = 0; mf < 4; ++mf)
            #pragma unroll
            for (int nf = 0; nf < 4; ++nf){
                int row = m0 + wr * 64 + mf * 16 + 4 * (lane >> 4);
                int col = n0 + wc * 64 + nf * 16 + (lane & 15);
                int bb = row >> 11, ll = row & 2047;
                int bh = bb * 16 + (col >> 6), dd = col & 63;
                f16x4 o = { (f16)acc[mf][nf][0], (f16)acc[mf][nf][1],
                            (f16)acc[mf][nf][2], (f16)acc[mf][nf][3] };
                *(f16x4*)&vtout[((size_t)(bh * 64 + dd)) * 2048 + ll] = o;
            }
    } else {
        #pragma unroll
        for (int mf = 0; mf < 4; ++mf)
            #pragma unroll
            for (int nf = 0; nf < 4; ++nf)
                #pragma unroll
                for (int r = 0; r < 4; ++r){
                    int row = m0 + wr * 64 + mf * 16 + 4 * (lane >> 4) + r;
                    int col = n0 + wc * 64 + nf * 16 + (lane & 15);
                    out[(size_t)row * N + col] = (OutT)acc[mf][nf][r];
                }
    }
}

// ---------- GEMM 64x128 (proj): 512 blocks -> 2 blocks/CU, 8 waves/CU ----------
__global__ __launch_bounds__(256) void gemm_proj64(
    const f16* __restrict__ A, const f16* __restrict__ W,
    float* __restrict__ out, int M, int N, int K)
{
    const int tid  = threadIdx.x;
    const int lane = tid & 63;
    const int wc   = tid >> 6;           // wave owns 64 x 32 output
    const int g    = lane >> 4;
    const int qq   = lane & 15;
    const int m0   = blockIdx.y * 64;
    const int n0   = blockIdx.x * 128;

    __shared__ f16 At[2][64 * 64];
    __shared__ f16 Bt[2][128 * 64];

    f32x4 acc[4][2] = {};
    f16x8 avr[2], bvr[4];

    // A: 512 chunks of 16B (2/thread); B: 1024 chunks (4/thread)
    int arow[2], acol[2], aswz[2];
    #pragma unroll
    for (int j = 0; j < 2; ++j){
        int c  = j * 256 + tid;
        arow[j] = c >> 3; acol[j] = (c & 7) * 8;
        aswz[j] = arow[j] * 128 + (((c & 7) * 16) ^ ((arow[j] & 7) << 4));
    }
    int brow[4], bcol[4], bswz[4];
    #pragma unroll
    for (int j = 0; j < 4; ++j){
        int c  = j * 256 + tid;
        brow[j] = c >> 3; bcol[j] = (c & 7) * 8;
        bswz[j] = brow[j] * 128 + (((c & 7) * 16) ^ ((brow[j] & 7) << 4));
    }

    #pragma unroll
    for (int j = 0; j < 2; ++j) avr[j] = *(const f16x8*)&A[(size_t)(m0 + arow[j]) * K + acol[j]];
    #pragma unroll
    for (int j = 0; j < 4; ++j) bvr[j] = *(const f16x8*)&W[(size_t)(n0 + brow[j]) * K + bcol[j]];
    #pragma unroll
    for (int j = 0; j < 2; ++j) *(f16x8*)((char*)At[0] + aswz[j]) = avr[j];
    #pragma unroll
    for (int j = 0; j < 4; ++j) *(f16x8*)((char*)Bt[0] + bswz[j]) = bvr[j];
    __syncthreads();

    const int NT = K >> 6;
    for (int t = 0; t < NT; ++t){
        const int cur = t & 1;
        const bool pre = (t + 1 < NT);
        if (pre){
            const int k0 = (t + 1) << 6;
            #pragma unroll
            for (int j = 0; j < 2; ++j) avr[j] = *(const f16x8*)&A[(size_t)(m0 + arow[j]) * K + k0 + acol[j]];
            #pragma unroll
            for (int j = 0; j < 4; ++j) bvr[j] = *(const f16x8*)&W[(size_t)(n0 + brow[j]) * K + k0 + bcol[j]];
        }
        #pragma unroll
        for (int kk = 0; kk < 2; ++kk){
            f16x8 af[4], bf[2];
            #pragma unroll
            for (int mf = 0; mf < 4; ++mf){
                int row = mf * 16 + qq;
                int cb  = (kk * 64 + 16 * g) ^ ((row & 7) << 4);
                af[mf] = *(const f16x8*)((const char*)At[cur] + row * 128 + cb);
            }
            #pragma unroll
            for (int nf = 0; nf < 2; ++nf){
                int row = wc * 32 + nf * 16 + qq;
                int cb  = (kk * 64 + 16 * g) ^ ((row & 7) << 4);
                bf[nf] = *(const f16x8*)((const char*)Bt[cur] + row * 128 + cb);
            }
            #pragma unroll
            for (int mf = 0; mf < 4; ++mf)
                #pragma unroll
                for (int nf = 0; nf < 2; ++nf)
                    acc[mf][nf] = mfma16(af[mf], bf[nf], acc[mf][nf]);
        }
        if (pre){
            const int nb = cur ^ 1;
            #pragma unroll
            for (int j = 0; j < 2; ++j) *(f16x8*)((char*)At[nb] + aswz[j]) = avr[j];
            #pragma unroll
            for (int j = 0; j < 4; ++j) *(f16x8*)((char*)Bt[nb] + bswz[j]) = bvr[j];
        }
        __syncthreads();
    }
    #pragma unroll
    for (int mf = 0; mf < 4; ++mf)
        #pragma unroll
        for (int nf = 0; nf < 2; ++nf)
            #pragma unroll
            for (int r = 0; r < 4; ++r){
                int row = m0 + mf * 16 + 4 * g + r;
                int col = n0 + wc * 32 + nf * 16 + qq;
                out[(size_t)row * N + col] = acc[mf][nf][r];
            }
}

// ---------- fused causal flash attention (split-k; rule-18 P fence) ----------
__global__ __launch_bounds__(256, 4) void attn_fused(
    const f16* __restrict__ q, const f16* __restrict__ k,
    const f16* __restrict__ vt, const int* __restrict__ amask,
    f16* __restrict__ y, float* __restrict__ pO, float* __restrict__ pML)
{
    const int tid  = threadIdx.x;
    const int lane = tid & 63;
    const int w    = tid >> 6;
    const int g    = lane >> 4;
    const int qq   = lane & 15;

    const int lin = blockIdx.x;
    const int bh  = lin & 31;
    const int grp = lin >> 5;
    int qt, ktLo, ktHi, part; bool fin;
    if (grp < 4)      { qt = 19 - grp;  ktLo = 0;  ktHi = qt + 1; fin = true;  part = 0; }
    else if (grp < 16){ qt = 16 + grp;  ktLo = 0;  ktHi = 16;     fin = false; part = 0; }
    else if (grp < 28){ qt = 47 - grp;  ktLo = 16; ktHi = qt + 1; fin = false; part = 1; }
    else              { qt = 43 - grp;  ktLo = 0;  ktHi = qt + 1; fin = true;  part = 0; }

    const int b = bh >> 4, h = bh & 15;
    const int q0w = qt * 64 + w * 16;

    __shared__ char sK[2][64 * 128];
    __shared__ char sV[2][64 * 128];
    __shared__ char sP[4][16 * 128];

    const int srow = (tid * 2) >> 3;
    const int sc8a = (tid * 2) & 7, sc8b = sc8a + 1;
    const int swka = (sc8a * 16) ^ ((srow & 7) << 4);
    const int swkb = (sc8b * 16) ^ ((srow & 7) << 4);
    const f16* kbase  = k  + ((size_t)b * 2048) * 1024 + h * 64;
    const f16* vtbase = vt + (size_t)bh * 64 * 2048;

    const f16 qscale = (f16)(0.125f * 1.44269504088896f);
    f16x8 aq[2];
    #pragma unroll
    for (int f = 0; f < 2; ++f){
        aq[f] = *(const f16x8*)&q[((size_t)(b * 2048 + q0w + qq)) * 1024 + h * 64 + f * 32 + 8 * g];
        #pragma unroll
        for (int j = 0; j < 8; ++j) aq[f][j] *= qscale;
    }

    f32x4 acc_o[4] = {};
    float m_ln = LNEG, l_ln = 0.f;

    char* pbase = sP[w] + qq * 128;
    const int swp = (qq & 7) << 4;

    {
        const int k0p = ktLo * 64;
        f16x8 ka  = *(const f16x8*)(kbase  + (size_t)(k0p + srow) * 1024 + sc8a * 8);
        f16x8 kb2 = *(const f16x8*)(kbase  + (size_t)(k0p + srow) * 1024 + sc8b * 8);
        f16x8 va  = *(const f16x8*)(vtbase + (size_t)srow * 2048 + k0p + sc8a * 8);
        f16x8 vb  = *(const f16x8*)(vtbase + (size_t)srow * 2048 + k0p + sc8b * 8);
        *(f16x8*)(sK[0] + srow * 128 + swka) = ka;
        *(f16x8*)(sK[0] + srow * 128 + swkb) = kb2;
        *(f16x8*)(sV[0] + srow * 128 + swka) = va;
        *(f16x8*)(sV[0] + srow * 128 + swkb) = vb;
    }
    __syncthreads();

    for (int kt = ktLo; kt < ktHi; ++kt){
        const int cur = (kt - ktLo) & 1;
        const int k0 = kt * 64;
        const bool pre = (kt + 1 < ktHi);

        f16x8 ka, kb2, va, vb;
        if (pre){
            const int nk0 = k0 + 64;
            ka  = *(const f16x8*)(kbase  + (size_t)(nk0 + srow) * 1024 + sc8a * 8);
            kb2 = *(const f16x8*)(kbase  + (size_t)(nk0 + srow) * 1024 + sc8b * 8);
            va  = *(const f16x8*)(vtbase + (size_t)srow * 2048 + nk0 + sc8a * 8);
            vb  = *(const f16x8*)(vtbase + (size_t)srow * 2048 + nk0 + sc8b * 8);
        }

        unsigned long long tokbits = __ballot(amask[b * 2048 + k0 + lane] != 0);
        const bool tokall = (tokbits == ~0ull);

        f32x4 acc_s[4] = {};
        #pragma unroll
        for (int kf = 0; kf < 4; ++kf){
            const int keyl = kf * 16 + qq;
            const char* kr = sK[cur] + keyl * 128;
            const int sw = (keyl & 7) << 4;
            #pragma unroll
            for (int f = 0; f < 2; ++f){
                f16x8 ak = *(const f16x8*)(kr + ((f * 64 + 16 * g) ^ sw));
                acc_s[kf] = mfma16(ak, aq[f], acc_s[kf]);
            }
        }

        const bool fullt = (k0 + 63 <= q0w) && tokall;
        float sv[16];
        #pragma unroll
        for (int kf = 0; kf < 4; ++kf)
            #pragma unroll
            for (int r = 0; r < 4; ++r){
                float s = acc_s[kf][r];
                if (!fullt){
                    const int keyl = kf * 16 + 4 * g + r;
                    const bool ok = (k0 + keyl <= q0w + qq) && ((tokbits >> keyl) & 1);
                    s = ok ? s : LNEG;
                }
                sv[kf * 4 + r] = s;
            }

        float tmax = sv[0];
        #pragma unroll
        for (int i = 1; i < 16; ++i) tmax = fmaxf(tmax, sv[i]);
        tmax = fmaxf(tmax, __shfl_xor(tmax, 16));
        tmax = fmaxf(tmax, __shfl_xor(tmax, 32));
        const bool skip = __all(tmax <= m_ln + 8.f);   // defer-max (log2 units)
        float alpha = 1.f;
        if (!skip){
            const float newm = fmaxf(m_ln, tmax);
            alpha = EXP2(m_ln - newm);
            m_ln = newm;
        }
        float rs = 0.f;
        #pragma unroll
        for (int i = 0; i < 16; ++i){ sv[i] = EXP2(sv[i] - m_ln); rs += sv[i]; }
        rs += __shfl_xor(rs, 16);
        rs += __shfl_xor(rs, 32);
        l_ln = l_ln * alpha + rs;
        if (!skip){
            #pragma unroll
            for (int r = 0; r < 4; ++r){
                const float ar = __shfl(alpha, 4 * g + r);
                #pragma unroll
                for (int nf = 0; nf < 4; ++nf) acc_o[nf][r] *= ar;
            }
        }

        #pragma unroll
        for (int kf = 0; kf < 4; ++kf){
            f16x4 pk = { (f16)sv[kf*4+0], (f16)sv[kf*4+1], (f16)sv[kf*4+2], (f16)sv[kf*4+3] };
            *(f16x4*)(pbase + ((kf * 32 + 8 * g) ^ swp)) = pk;
        }
        // rule-18 wave-local fence: P stores drain before P reads; sP[w] is
        // wave-private so no cross-wave barrier needed here.
        asm volatile("s_waitcnt lgkmcnt(0)" ::: "memory");
        __builtin_amdgcn_sched_barrier(0);

        #pragma unroll
        for (int f = 0; f < 2; ++f){
            f16x8 ap = *(const f16x8*)(pbase + ((f * 64 + 16 * g) ^ swp));
            #pragma unroll
            for (int nf = 0; nf < 4; ++nf){
                const int d = nf * 16 + qq;
                f16x8 bv = *(const f16x8*)(sV[cur] + d * 128 + ((f * 64 + 16 * g) ^ ((d & 7) << 4)));
                acc_o[nf] = mfma16(ap, bv, acc_o[nf]);
            }
        }

        if (pre){
            const int nb = cur ^ 1;
            *(f16x8*)(sK[nb] + srow * 128 + swka) = ka;
            *(f16x8*)(sK[nb] + srow * 128 + swkb) = kb2;
            *(f16x8*)(sV[nb] + srow * 128 + swka) = va;
            *(f16x8*)(sV[nb] + srow * 128 + swkb) = vb;
        }
        __syncthreads();   // staging visible + P reads done before next overwrite
    }

    if (fin){
        const float invl = 1.f / l_ln;
        #pragma unroll
        for (int r = 0; r < 4; ++r){
            const float ir = __shfl(invl, 4 * g + r);
            const int row = q0w + 4 * g + r;
            #pragma unroll
            for (int nf = 0; nf < 4; ++nf)
                y[((size_t)(b * 2048 + row)) * 1024 + h * 64 + nf * 16 + qq] = (f16)(acc_o[nf][r] * ir);
        }
    } else {
        const int qi = qt - 20;
        const size_t base = (((size_t)part * 12 + qi) * 32 + bh) * 64;
        #pragma unroll
        for (int r = 0; r < 4; ++r){
            const int row_local = w * 16 + 4 * g + r;
            float* po = pO + (base + row_local) * 64;
            #pragma unroll
            for (int nf = 0; nf < 4; ++nf)
                po[nf * 16 + qq] = acc_o[nf][r];
        }
        if (lane < 16){
            const size_t mlb = (base + w * 16 + lane) * 2;
            pML[mlb]     = m_ln;
            pML[mlb + 1] = l_ln;
        }
    }
}

// ---------- merge partials for qt 20..31 (rows 1280..2047) ----------
__global__ __launch_bounds__(256) void attn_merge(
    const float* __restrict__ pO, const float* __restrict__ pML, f16* __restrict__ y)
{
    const int t = blockIdx.x * 256 + threadIdx.x;
    const int dc = (t & 3) * 16;
    const int rowg = t >> 2;
    const int row = rowg & 63;
    const int bh  = (rowg >> 6) & 31;
    const int qi  = rowg >> 11;
    const size_t rbase = ((size_t)qi * 32 + bh) * 64 + row;
    const size_t PST = (size_t)12 * 32 * 64;

    const float mA = pML[rbase * 2],         lA = pML[rbase * 2 + 1];
    const float mB = pML[(PST + rbase) * 2], lB = pML[(PST + rbase) * 2 + 1];
    const float m  = fmaxf(mA, mB);
    const float wA = EXP2(mA - m), wB = EXP2(mB - m);
    const float inv = 1.f / (wA * lA + wB * lB);

    const float4* oA = (const float4*)(pO + rbase * 64 + dc);
    const float4* oB = (const float4*)(pO + (PST * 64) + rbase * 64 + dc);
    float ov[16];
    #pragma unroll
    for (int j = 0; j < 4; ++j){
        float4 a = oA[j], bb4 = oB[j];
        ov[j*4+0] = (wA * a.x + wB * bb4.x) * inv;
        ov[j*4+1] = (wA * a.y + wB * bb4.y) * inv;
        ov[j*4+2] = (wA * a.z + wB * bb4.z) * inv;
        ov[j*4+3] = (wA * a.w + wB * bb4.w) * inv;
    }
    const int b = bh >> 4, h = bh & 15;
    const int grow = (20 + qi) * 64 + row;
    f16* yp = &y[((size_t)(b * 2048 + grow)) * 1024 + h * 64 + dc];
    f16x8 o0 = { (f16)ov[0],(f16)ov[1],(f16)ov[2],(f16)ov[3],(f16)ov[4],(f16)ov[5],(f16)ov[6],(f16)ov[7] };
    f16x8 o1 = { (f16)ov[8],(f16)ov[9],(f16)ov[10],(f16)ov[11],(f16)ov[12],(f16)ov[13],(f16)ov[14],(f16)ov[15] };
    *(f16x8*)yp = o0;
    *(f16x8*)(yp + 8) = o1;
}

extern "C" void kernel_launch(void* const* d_in, const int* in_sizes, int n_in,
                              void* d_out, int out_size, void* d_ws, size_t ws_size,
                              hipStream_t stream){
    const float* x  = (const float*)d_in[0];
    const int*   am = (const int*)d_in[1];
    const float* Wq = (const float*)d_in[2];
    const float* Wk = (const float*)d_in[3];
    const float* Wv = (const float*)d_in[4];
    const float* Wp = (const float*)d_in[5];
    float* out = (float*)d_out;

    char* ws = (char*)d_ws;
    const size_t XE = (size_t)4096 * 1024;
    const size_t WE = (size_t)1024 * 1024;

    f16* x16 = (f16*)(ws);
    f16* w16 = (f16*)(ws + XE * 2);
    f16* qkv = (f16*)(ws + XE * 2 + WE * 8);
    f16* vt  = (f16*)(ws + XE * 2 + WE * 8 + XE * 6);
    f16* y16 = (f16*)(ws + XE * 2 + WE * 8 + XE * 8);
    float* pO  = (float*)ws;
    float* pML = (float*)(ws + (size_t)2*12*32*64*64*4);

    cvt5<<<4096, 256, 0, stream>>>(x, Wq, Wk, Wv, Wp, x16, (int)(XE / 8));

    gemm_xwt<f16><<<dim3(8, 32, 3), 256, 0, stream>>>(x16, w16, WE, qkv, XE, vt, 4096, 1024, 1024);

    attn_fused<<<dim3(1408), 256, 0, stream>>>(qkv, qkv + XE, vt, am, y16, pO, pML);

    attn_merge<<<384, 256, 0, stream>>>(pO, pML, y16);

    gemm_proj64<<<dim3(8, 64), 256, 0, stream>>>(y16, w16 + 3 * WE, out, 4096, 1024, 1024);
}